// Round 1
// 473.539 us; speedup vs baseline: 1.0720x; 1.0720x over previous
//
#include <hip/hip_runtime.h>
#include <cstdint>
#include <cstddef>

#define B_ 256
#define S_ 128
#define H_ 512
#define E_ 512
#define V_ 32000
#define NBLK_G (V_ / 64)   // 500 column blocks in score_g GEMM

typedef _Float16 half_t;
typedef _Float16 half8 __attribute__((ext_vector_type(8)));
typedef float floatx4 __attribute__((ext_vector_type(4)));

__device__ __forceinline__ float sigmoidf_(float x) { return 1.0f / (1.0f + __expf(-x)); }
__device__ __forceinline__ float fast_tanh(float x) {
    float e = __expf(2.0f * x);           // +-inf safe: -> -1 / +1
    return 1.0f - 2.0f / (e + 1.0f);
}

// ---------------------------------------------------------------------------
// prep: x = [embed[ids], weighted_eff] (B,1536), prev_eff (B,512).
// ---------------------------------------------------------------------------
__global__ __launch_bounds__(256)
void prep_kernel(const int* __restrict__ ids, const float* __restrict__ encoded,
                 const float* __restrict__ prev_state, const float* __restrict__ weighted,
                 const int* __restrict__ order_p, const float* __restrict__ embed,
                 const float* __restrict__ Ws_w, const float* __restrict__ Ws_b,
                 float* __restrict__ x, float* __restrict__ prev)
{
    int i = blockIdx.x * 256 + threadIdx.x;   // B_ * 2048 threads
    int b = i >> 11;
    int j = i & 2047;
    int order = order_p[0];
    if (j < 1536) {
        float v;
        if (j < 512) v = embed[(size_t)ids[b] * E_ + j];
        else         v = (order == 0) ? 0.0f : weighted[b * 1024 + (j - 512)];
        x[b * 1536 + j] = v;
    } else {
        int h = j - 1536;
        float v;
        if (order != 0) {
            v = prev_state[b * H_ + h];
        } else {
            const float* e  = encoded + ((size_t)b * S_ + (S_ - 1)) * 1024;
            const float* wr = Ws_w + (size_t)h * 1024;
            float accv = Ws_b[h];
            for (int k = 0; k < 1024; ++k) accv += e[k] * wr[k];
            v = accv;
        }
        prev[b * H_ + h] = v;
    }
}

// ---------------------------------------------------------------------------
// Wc fp32 (512x1024) -> f16 row-major, once per launch. 2 MB read, 1 MB write.
// ---------------------------------------------------------------------------
__global__ __launch_bounds__(256)
void wc_cvt_kernel(const float* __restrict__ Wc, half_t* __restrict__ out)
{
    int i = blockIdx.x * 256 + threadIdx.x;    // 65536 items of 8 elements
    const float* p = Wc + (size_t)i * 8;
    float4 a = *(const float4*)p;
    float4 b = *(const float4*)(p + 4);
    half8 h;
    h[0] = (half_t)a.x; h[1] = (half_t)a.y; h[2] = (half_t)a.z; h[3] = (half_t)a.w;
    h[4] = (half_t)b.x; h[5] = (half_t)b.y; h[6] = (half_t)b.z; h[7] = (half_t)b.w;
    *(half8*)(out + (size_t)i * 8) = h;
}

// ---------------------------------------------------------------------------
// Generic fp32-in / fp16-MFMA GEMM: C[m,n] = sum_k A[m,k]*Bw[n,k] + bias[n]
// XOR-swizzled LDS (no padding, 16-B ops, bank-balanced).
// EPI==0: plain write. EPI==2: write + per-(row, block) softmax partials
//         aux[m*nblk+bx] = rowmax, aux[256*nblk + m*nblk+bx] = sumexp.
// ---------------------------------------------------------------------------
template<int BM, int BN, int WAVES_M, int WAVES_N, int EPI>
__global__ __launch_bounds__(256, 2)
void gemm_f16(const float* __restrict__ A, const float* __restrict__ Bw,
              float* __restrict__ C, const float* __restrict__ bias,
              float* __restrict__ aux, int K, int lda, int ldb, int ldc, int nblk)
{
    constexpr int BK = 32;
    constexpr int WM = BM / WAVES_M;
    constexpr int WN = BN / WAVES_N;
    constexpr int FM = WM / 16;
    constexpr int FN = WN / 16;
    constexpr int A_ITEMS = (BM * 4) / 256;   // items of 8 floats
    constexpr int B_ITEMS = (BN * 4) / 256;

    __shared__ half_t As[BM * BK];
    __shared__ half_t Bs[BN * BK];

    const int tid  = threadIdx.x;
    const int wid  = tid >> 6;
    const int lane = tid & 63;
    const int wm   = wid % WAVES_M;
    const int wn   = wid / WAVES_M;
    const int bm0  = blockIdx.y * BM;
    const int bn0  = blockIdx.x * BN;
    const int col  = lane & 15;
    const int quad = lane >> 4;
    const int swz  = (quad ^ (col & 3)) * 8;

    floatx4 acc[FM][FN] = {};

    for (int kt = 0; kt < K; kt += BK) {
        float4 ar[A_ITEMS][2], br[B_ITEMS][2];
#pragma unroll
        for (int i = 0; i < A_ITEMS; ++i) {
            int idx = tid + i * 256, row = idx >> 2, ch = idx & 3;
            const float* p = A + (size_t)(bm0 + row) * lda + kt + ch * 8;
            ar[i][0] = *(const float4*)p; ar[i][1] = *(const float4*)(p + 4);
        }
#pragma unroll
        for (int i = 0; i < B_ITEMS; ++i) {
            int idx = tid + i * 256, row = idx >> 2, ch = idx & 3;
            const float* p = Bw + (size_t)(bn0 + row) * ldb + kt + ch * 8;
            br[i][0] = *(const float4*)p; br[i][1] = *(const float4*)(p + 4);
        }
        __syncthreads();   // prior iteration's LDS reads done
#pragma unroll
        for (int i = 0; i < A_ITEMS; ++i) {
            int idx = tid + i * 256, row = idx >> 2, ch = idx & 3;
            int pos = (ch ^ (row & 3)) * 8;
            half8 h;
            h[0] = (half_t)ar[i][0].x; h[1] = (half_t)ar[i][0].y;
            h[2] = (half_t)ar[i][0].z; h[3] = (half_t)ar[i][0].w;
            h[4] = (half_t)ar[i][1].x; h[5] = (half_t)ar[i][1].y;
            h[6] = (half_t)ar[i][1].z; h[7] = (half_t)ar[i][1].w;
            *(half8*)(&As[row * BK + pos]) = h;
        }
#pragma unroll
        for (int i = 0; i < B_ITEMS; ++i) {
            int idx = tid + i * 256, row = idx >> 2, ch = idx & 3;
            int pos = (ch ^ (row & 3)) * 8;
            half8 h;
            h[0] = (half_t)br[i][0].x; h[1] = (half_t)br[i][0].y;
            h[2] = (half_t)br[i][0].z; h[3] = (half_t)br[i][0].w;
            h[4] = (half_t)br[i][1].x; h[5] = (half_t)br[i][1].y;
            h[6] = (half_t)br[i][1].z; h[7] = (half_t)br[i][1].w;
            *(half8*)(&Bs[row * BK + pos]) = h;
        }
        __syncthreads();

        half8 af[FM], bf[FN];
#pragma unroll
        for (int fm = 0; fm < FM; ++fm)
            af[fm] = *(const half8*)(&As[(wm * WM + fm * 16 + col) * BK + swz]);
#pragma unroll
        for (int fn = 0; fn < FN; ++fn)
            bf[fn] = *(const half8*)(&Bs[(wn * WN + fn * 16 + col) * BK + swz]);
#pragma unroll
        for (int fm = 0; fm < FM; ++fm)
#pragma unroll
            for (int fn = 0; fn < FN; ++fn)
                acc[fm][fn] = __builtin_amdgcn_mfma_f32_16x16x32_f16(af[fm], bf[fn], acc[fm][fn], 0, 0, 0);
    }

    if constexpr (EPI == 0) {
#pragma unroll
        for (int fm = 0; fm < FM; ++fm) {
            int m0 = bm0 + wm * WM + fm * 16 + quad * 4;
#pragma unroll
            for (int fn = 0; fn < FN; ++fn) {
                int n = bn0 + wn * WN + fn * 16 + col;
                float bv = bias[n];
#pragma unroll
                for (int r = 0; r < 4; ++r)
                    C[(size_t)(m0 + r) * ldc + n] = acc[fm][fn][r] + bv;
            }
        }
    } else {   // EPI == 2 : write + softmax partials (WAVES_N must be 1)
        const int bx = blockIdx.x;
#pragma unroll
        for (int fm = 0; fm < FM; ++fm) {
            int m0 = bm0 + wm * WM + fm * 16 + quad * 4;
            float vv[FN][4];
#pragma unroll
            for (int fn = 0; fn < FN; ++fn) {
                int n = bn0 + fn * 16 + col;
                float bv = bias[n];
#pragma unroll
                for (int r = 0; r < 4; ++r) {
                    vv[fn][r] = acc[fm][fn][r] + bv;
                    C[(size_t)(m0 + r) * ldc + n] = vv[fn][r];
                }
            }
#pragma unroll
            for (int r = 0; r < 4; ++r) {
                float mx = vv[0][r];
#pragma unroll
                for (int fn = 1; fn < FN; ++fn) mx = fmaxf(mx, vv[fn][r]);
#pragma unroll
                for (int off = 1; off < 16; off <<= 1)
                    mx = fmaxf(mx, __shfl_xor(mx, off, 64));
                float se = 0.f;
#pragma unroll
                for (int fn = 0; fn < FN; ++fn) se += __expf(vv[fn][r] - mx);
#pragma unroll
                for (int off = 1; off < 16; off <<= 1)
                    se += __shfl_xor(se, off, 64);
                if (col == 0) {
                    aux[(size_t)(m0 + r) * nblk + bx] = mx;
                    aux[(size_t)256 * nblk + (size_t)(m0 + r) * nblk + bx] = se;
                }
            }
        }
    }
}

// ---------------------------------------------------------------------------
// Wc GEMM + fused tanh-einsum, one block owns ALL N=512:
// sc_out[m] = sum_n tanh(enc[m,:]@Wc[n,:] + bias[n]) * hidden[b(m), n]
// v2: B fragments read directly from L2 (f16 pre-converted Wc, 1 MB resident),
//     A double-buffered in LDS (4 KB/buf), one barrier/iter, loads for tile
//     t+1 issued right after the barrier so latency hides under MFMAs.
// 512 threads, 8 waves (WAVES_M=1, WAVES_N=8), BM=64, grid=512, 2 blocks/CU.
// ---------------------------------------------------------------------------
__global__ __launch_bounds__(512, 4)
void wc_sc_kernel(const float* __restrict__ enc, const half_t* __restrict__ WcH,
                  const float* __restrict__ bias, const float* __restrict__ hidden,
                  float* __restrict__ sc_out)
{
    __shared__ half_t As[2][64 * 32];   // 2 x 4 KB, XOR-swizzled
    __shared__ float  s_part[8 * 64];

    const int tid  = threadIdx.x;
    const int wid  = tid >> 6;          // wave -> col group of 64
    const int lane = tid & 63;
    const int col  = lane & 15;
    const int quad = lane >> 4;
    const int swz  = (quad ^ (col & 3)) * 8;
    const int bm0  = blockIdx.x * 64;

    // A staging mapping (tid < 256): row = tid>>2, 8-float chunk = tid&3
    const int ar_row = tid >> 2;
    const int ar_ch  = tid & 3;
    const float* aptr = enc + (size_t)(bm0 + ar_row) * 1024 + ar_ch * 8;
    const int a_pos = ar_row * 32 + (ar_ch ^ (ar_row & 3)) * 8;

    // B fragment base pointers: lane (col,quad) of fragment fn reads
    // WcH[n = wid*64 + fn*16 + col][k = kt + quad*8 .. +7]
    const half_t* bptr0 = WcH + (size_t)(wid * 64 +  0 + col) * 1024 + quad * 8;
    const half_t* bptr1 = WcH + (size_t)(wid * 64 + 16 + col) * 1024 + quad * 8;
    const half_t* bptr2 = WcH + (size_t)(wid * 64 + 32 + col) * 1024 + quad * 8;
    const half_t* bptr3 = WcH + (size_t)(wid * 64 + 48 + col) * 1024 + quad * 8;

    floatx4 acc[4][4] = {};
    float4 ar0, ar1;
    half8 bf0[4], bf1[4];

    // prologue: issue loads for tile 0
    if (tid < 256) { ar0 = *(const float4*)(aptr); ar1 = *(const float4*)(aptr + 4); }
    bf0[0] = *(const half8*)(bptr0);
    bf0[1] = *(const half8*)(bptr1);
    bf0[2] = *(const half8*)(bptr2);
    bf0[3] = *(const half8*)(bptr3);

    for (int t2 = 0; t2 < 16; ++t2) {
        const int kA = t2 * 64;
        // ---------- phase A: tile kA, As[0], bf0 ----------
        if (tid < 256) {
            half8 h;
            h[0] = (half_t)ar0.x; h[1] = (half_t)ar0.y; h[2] = (half_t)ar0.z; h[3] = (half_t)ar0.w;
            h[4] = (half_t)ar1.x; h[5] = (half_t)ar1.y; h[6] = (half_t)ar1.z; h[7] = (half_t)ar1.w;
            *(half8*)(&As[0][a_pos]) = h;
        }
        __syncthreads();
        // issue loads for tile kA+32 (hide under phase-A MFMAs)
        if (tid < 256) {
            ar0 = *(const float4*)(aptr + kA + 32);
            ar1 = *(const float4*)(aptr + kA + 36);
        }
        bf1[0] = *(const half8*)(bptr0 + kA + 32);
        bf1[1] = *(const half8*)(bptr1 + kA + 32);
        bf1[2] = *(const half8*)(bptr2 + kA + 32);
        bf1[3] = *(const half8*)(bptr3 + kA + 32);
#pragma unroll
        for (int fm = 0; fm < 4; ++fm) {
            half8 af = *(const half8*)(&As[0][(fm * 16 + col) * 32 + swz]);
#pragma unroll
            for (int fn = 0; fn < 4; ++fn)
                acc[fm][fn] = __builtin_amdgcn_mfma_f32_16x16x32_f16(af, bf0[fn], acc[fm][fn], 0, 0, 0);
        }
        // ---------- phase B: tile kA+32, As[1], bf1 ----------
        if (tid < 256) {
            half8 h;
            h[0] = (half_t)ar0.x; h[1] = (half_t)ar0.y; h[2] = (half_t)ar0.z; h[3] = (half_t)ar0.w;
            h[4] = (half_t)ar1.x; h[5] = (half_t)ar1.y; h[6] = (half_t)ar1.z; h[7] = (half_t)ar1.w;
            *(half8*)(&As[1][a_pos]) = h;
        }
        __syncthreads();
        if (kA + 64 < 1024) {   // issue loads for tile kA+64
            if (tid < 256) {
                ar0 = *(const float4*)(aptr + kA + 64);
                ar1 = *(const float4*)(aptr + kA + 68);
            }
            bf0[0] = *(const half8*)(bptr0 + kA + 64);
            bf0[1] = *(const half8*)(bptr1 + kA + 64);
            bf0[2] = *(const half8*)(bptr2 + kA + 64);
            bf0[3] = *(const half8*)(bptr3 + kA + 64);
        }
#pragma unroll
        for (int fm = 0; fm < 4; ++fm) {
            half8 af = *(const half8*)(&As[1][(fm * 16 + col) * 32 + swz]);
#pragma unroll
            for (int fn = 0; fn < 4; ++fn)
                acc[fm][fn] = __builtin_amdgcn_mfma_f32_16x16x32_f16(af, bf1[fn], acc[fm][fn], 0, 0, 0);
        }
    }

    // fused epilogue: tanh + dot with hidden, reduce over n
    const float* hid = hidden + (size_t)(bm0 >> 7) * H_;
#pragma unroll
    for (int fm = 0; fm < 4; ++fm) {
        float p0 = 0.f, p1 = 0.f, p2 = 0.f, p3 = 0.f;
#pragma unroll
        for (int fn = 0; fn < 4; ++fn) {
            int n = wid * 64 + fn * 16 + col;
            float bv = bias[n];
            float hv = hid[n];
            p0 += fast_tanh(acc[fm][fn][0] + bv) * hv;
            p1 += fast_tanh(acc[fm][fn][1] + bv) * hv;
            p2 += fast_tanh(acc[fm][fn][2] + bv) * hv;
            p3 += fast_tanh(acc[fm][fn][3] + bv) * hv;
        }
#pragma unroll
        for (int off = 1; off < 16; off <<= 1) {
            p0 += __shfl_xor(p0, off, 64);
            p1 += __shfl_xor(p1, off, 64);
            p2 += __shfl_xor(p2, off, 64);
            p3 += __shfl_xor(p3, off, 64);
        }
        if (col == 0) {
            int rloc = fm * 16 + quad * 4;   // [0,64)
            s_part[wid * 64 + rloc + 0] = p0;
            s_part[wid * 64 + rloc + 1] = p1;
            s_part[wid * 64 + rloc + 2] = p2;
            s_part[wid * 64 + rloc + 3] = p3;
        }
    }
    __syncthreads();
    if (tid < 64) {
        float s = 0.f;
#pragma unroll
        for (int w = 0; w < 8; ++w) s += s_part[w * 64 + tid];
        sc_out[bm0 + tid] = s;
    }
}

// ---------------------------------------------------------------------------
// GRU gates
// ---------------------------------------------------------------------------
__global__ __launch_bounds__(256)
void gate_kernel(const float* __restrict__ gi, const float* __restrict__ gh,
                 const float* __restrict__ prev, float* __restrict__ hidden)
{
    int i = blockIdx.x * 256 + threadIdx.x;   // B_*H_
    int b = i >> 9;
    int h = i & 511;
    const float* gib = gi + (size_t)b * 1536;
    const float* ghb = gh + (size_t)b * 1536;
    float r = sigmoidf_(gib[h] + ghb[h]);
    float z = sigmoidf_(gib[h + 512] + ghb[h + 512]);
    float n = tanhf(gib[h + 1024] + r * ghb[h + 1024]);
    hidden[i] = (1.0f - z) * n + z * prev[i];
}

// ---------------------------------------------------------------------------
// final: merge softmax partials (from score_g GEMM epilogue) + copy scores,
// single in-place exp pass over predicted (float4), scatter, weighted_out.
// ---------------------------------------------------------------------------
__global__ __launch_bounds__(256)
void final_kernel(const float* __restrict__ sc_raw,
                  const int* __restrict__ src, const int* __restrict__ ids,
                  const float* __restrict__ encoded, const float* __restrict__ parts,
                  float* __restrict__ predicted, float* __restrict__ weighted_out)
{
    int b = blockIdx.x;
    int t = threadIdx.x;
    __shared__ float s_scf[S_];
    __shared__ float s_attn[S_];
    __shared__ int   s_src[S_];
    __shared__ float rm[4], rs[4];
    __shared__ int   s_cnt;

    float* pred = predicted + (size_t)b * V_;
    const float* pm = parts + (size_t)b * NBLK_G;
    const float* ps = parts + (size_t)256 * NBLK_G + (size_t)b * NBLK_G;

    if (t < S_) {
        int sv = src[b * S_ + t];
        s_src[t] = sv;
        float raw = sc_raw[b * S_ + t];
        if (sv == 0) raw -= 1000.0f;
        s_scf[t] = tanhf(raw);
    }

    // merge (max, sumexp) partials
    float m = -1e30f, s = 0.f;
    for (int j = t; j < NBLK_G; j += 256) {
        float mo = pm[j], so = ps[j];
        float mn = fmaxf(m, mo);
        s = s * __expf(m - mn) + so * __expf(mo - mn);
        m = mn;
    }
    __syncthreads();
    if (t < S_) {
        float x = s_scf[t];
        float mn = fmaxf(m, x);
        s = s * __expf(m - mn) + __expf(x - mn);
        m = mn;
    }
#pragma unroll
    for (int off = 1; off < 64; off <<= 1) {
        float mo = __shfl_xor(m, off, 64);
        float so = __shfl_xor(s, off, 64);
        float mn = fmaxf(m, mo);
        s = s * __expf(m - mn) + so * __expf(mo - mn);
        m = mn;
    }
    if ((t & 63) == 0) { rm[t >> 6] = m; rs[t >> 6] = s; }
    __syncthreads();
    float M = rm[0], Z = rs[0];
#pragma unroll
    for (int w = 1; w < 4; ++w) {
        float mo = rm[w], so = rs[w];
        float mn = fmaxf(M, mo);
        Z = Z * __expf(M - mn) + so * __expf(mo - mn);
        M = mn;
    }
    float invZ = 1.0f / Z;

    // in-place: predicted currently holds score_g
    float4* pr4 = (float4*)pred;
    for (int i = t; i < V_ / 4; i += 256) {
        float4 x = pr4[i];
        float4 o;
        o.x = __expf(x.x - M) * invZ;
        o.y = __expf(x.y - M) * invZ;
        o.z = __expf(x.z - M) * invZ;
        o.w = __expf(x.w - M) * invZ;
        pr4[i] = o;
    }

    int ii = ids[b];
    if (t == 0) {
        int c = 0;
        for (int s2 = 0; s2 < S_; ++s2) c += (s_src[s2] == ii) ? 1 : 0;
        s_cnt = (c > 0) ? c : 1;
    }
    __syncthreads();   // prob_g writes drained before scatter atomics

    if (t < S_) {
        float pc = __expf(s_scf[t] - M) * invZ;
        atomicAdd(&pred[s_src[t]], pc);
        s_attn[t] = (s_src[t] == ii) ? pc / (float)s_cnt : 0.f;
    }
    __syncthreads();

    const float* eb = encoded + (size_t)b * S_ * 1024;
    for (int d = t; d < 1024; d += 256) {
        float accv = 0.f;
        for (int s2 = 0; s2 < S_; ++s2) {
            float a = s_attn[s2];
            if (a != 0.f) accv += a * eb[s2 * 1024 + d];
        }
        weighted_out[b * 1024 + d] = accv;
    }
}

// ---------------------------------------------------------------------------
extern "C" void kernel_launch(void* const* d_in, const int* in_sizes, int n_in,
                              void* d_out, int out_size, void* d_ws, size_t ws_size,
                              hipStream_t stream)
{
    const int*   input_ids  = (const int*)d_in[0];
    const float* encoded    = (const float*)d_in[1];
    const int*   src        = (const int*)d_in[2];
    const float* prev_state = (const float*)d_in[3];
    const float* weighted   = (const float*)d_in[4];
    const int*   order      = (const int*)d_in[5];
    const float* embed_w    = (const float*)d_in[6];
    const float* gru_w_ih   = (const float*)d_in[7];
    const float* gru_w_hh   = (const float*)d_in[8];
    const float* gru_b_ih   = (const float*)d_in[9];
    const float* gru_b_hh   = (const float*)d_in[10];
    const float* Ws_w       = (const float*)d_in[11];
    const float* Ws_b       = (const float*)d_in[12];
    const float* Wo_w       = (const float*)d_in[13];
    const float* Wo_b       = (const float*)d_in[14];
    const float* Wc_w       = (const float*)d_in[15];
    const float* Wc_b       = (const float*)d_in[16];
    (void)in_sizes; (void)n_in; (void)out_size; (void)ws_size;

    float* predicted    = (float*)d_out;                       // B*V (holds score_g first)
    float* hidden       = predicted + (size_t)B_ * V_;         // B*H
    float* weighted_out = hidden + (size_t)B_ * H_;            // B*2H

    char* w = (char*)d_ws;
    float* x_f32  = (float*)w;  w += (size_t)B_ * 1536 * 4;
    float* prev_f = (float*)w;  w += (size_t)B_ * H_ * 4;
    float* gi     = (float*)w;  w += (size_t)B_ * 1536 * 4;
    float* gh     = (float*)w;  w += (size_t)B_ * 1536 * 4;
    float* sc_raw = (float*)w;  w += (size_t)B_ * S_ * 4;
    float* parts  = (float*)w;  w += (size_t)2 * B_ * NBLK_G * 4;
    half_t* wc_h  = (half_t*)w; w += (size_t)H_ * 1024 * 2;    // 1 MB f16 Wc

    // Wc -> f16 once (2 MB read), ahead of everything so L2 is warm for wc_sc
    wc_cvt_kernel<<<256, 256, 0, stream>>>(Wc_w, wc_h);

    prep_kernel<<<2048, 256, 0, stream>>>(input_ids, encoded, prev_state, weighted,
                                          order, embed_w, Ws_w, Ws_b, x_f32, prev_f);

    // gi = x @ W_ih^T + b_ih   (M=256, N=1536, K=1536)
    gemm_f16<64, 64, 2, 2, 0><<<dim3(1536 / 64, 256 / 64), 256, 0, stream>>>(
        x_f32, gru_w_ih, gi, gru_b_ih, nullptr, 1536, 1536, 1536, 1536, 0);
    // gh = prev @ W_hh^T + b_hh  (M=256, N=1536, K=512)
    gemm_f16<64, 64, 2, 2, 0><<<dim3(1536 / 64, 256 / 64), 256, 0, stream>>>(
        prev_f, gru_w_hh, gh, gru_b_hh, nullptr, 512, 512, 512, 1536, 0);

    gate_kernel<<<(B_ * H_) / 256, 256, 0, stream>>>(gi, gh, prev_f, hidden);

    // sc_raw[b,s] (fused tanh-einsum), encoded read exactly once
    wc_sc_kernel<<<(B_ * S_) / 64, 512, 0, stream>>>(encoded, wc_h, Wc_b, hidden, sc_raw);

    // score_g -> predicted (in-place later) + softmax partials
    gemm_f16<256, 64, 4, 1, 2><<<dim3(NBLK_G, 1), 256, 0, stream>>>(
        hidden, Wo_w, predicted, Wo_b, parts, 512, 512, 512, V_, NBLK_G);

    final_kernel<<<B_, 256, 0, stream>>>(sc_raw, src, input_ids, encoded, parts,
                                         predicted, weighted_out);
}

// Round 2
// 450.238 us; speedup vs baseline: 1.1275x; 1.0518x over previous
//
#include <hip/hip_runtime.h>
#include <cstdint>
#include <cstddef>

#define B_ 256
#define S_ 128
#define H_ 512
#define E_ 512
#define V_ 32000
#define NBLK_G (V_ / 64)   // 500 column blocks in score_g GEMM

typedef _Float16 half_t;
typedef _Float16 half8 __attribute__((ext_vector_type(8)));
typedef float floatx4 __attribute__((ext_vector_type(4)));

__device__ __forceinline__ float sigmoidf_(float x) { return 1.0f / (1.0f + __expf(-x)); }
__device__ __forceinline__ float fast_tanh(float x) {
    float e = __expf(2.0f * x);           // +-inf safe: -> -1 / +1
    return 1.0f - 2.0f / (e + 1.0f);
}

// ---------------------------------------------------------------------------
// prep: x = [embed[ids], weighted_eff] (B,1536), prev_eff (B,512).
// ---------------------------------------------------------------------------
__global__ __launch_bounds__(256)
void prep_kernel(const int* __restrict__ ids, const float* __restrict__ encoded,
                 const float* __restrict__ prev_state, const float* __restrict__ weighted,
                 const int* __restrict__ order_p, const float* __restrict__ embed,
                 const float* __restrict__ Ws_w, const float* __restrict__ Ws_b,
                 float* __restrict__ x, float* __restrict__ prev)
{
    int i = blockIdx.x * 256 + threadIdx.x;   // B_ * 2048 threads
    int b = i >> 11;
    int j = i & 2047;
    int order = order_p[0];
    if (j < 1536) {
        float v;
        if (j < 512) v = embed[(size_t)ids[b] * E_ + j];
        else         v = (order == 0) ? 0.0f : weighted[b * 1024 + (j - 512)];
        x[b * 1536 + j] = v;
    } else {
        int h = j - 1536;
        float v;
        if (order != 0) {
            v = prev_state[b * H_ + h];
        } else {
            const float* e  = encoded + ((size_t)b * S_ + (S_ - 1)) * 1024;
            const float* wr = Ws_w + (size_t)h * 1024;
            float accv = Ws_b[h];
            for (int k = 0; k < 1024; ++k) accv += e[k] * wr[k];
            v = accv;
        }
        prev[b * H_ + h] = v;
    }
}

// ---------------------------------------------------------------------------
// Wc fp32 (512x1024) -> f16 in MFMA-fragment-major layout:
//   out[(((nt*32 + kt)*4 + kq)*16 + nc)*8 + ke] = Wc[nt*16+nc][kt*32+kq*8+ke]
// so a wave's B-fragment load (lane = quad*16+col) is one contiguous 1 KB
// block: 16 B/lane, fully coalesced. Thread i owns output chunk i (coalesced
// writes); gather reads are 16 rows x 128 B runs. 2 MB read, 1 MB write.
// ---------------------------------------------------------------------------
__global__ __launch_bounds__(256)
void wc_cvt_kernel(const float* __restrict__ Wc, half_t* __restrict__ out)
{
    int i = blockIdx.x * 256 + threadIdx.x;    // 65536 chunks of 8 halfs
    int nc = i & 15;
    int kq = (i >> 4) & 3;
    int kt = (i >> 6) & 31;
    int nt = i >> 11;
    int n  = nt * 16 + nc;
    int k0 = kt * 32 + kq * 8;
    const float* p = Wc + (size_t)n * 1024 + k0;
    float4 a = *(const float4*)p;
    float4 b = *(const float4*)(p + 4);
    half8 h;
    h[0] = (half_t)a.x; h[1] = (half_t)a.y; h[2] = (half_t)a.z; h[3] = (half_t)a.w;
    h[4] = (half_t)b.x; h[5] = (half_t)b.y; h[6] = (half_t)b.z; h[7] = (half_t)b.w;
    *(half8*)(out + (size_t)i * 8) = h;
}

// ---------------------------------------------------------------------------
// Generic fp32-in / fp16-MFMA GEMM: C[m,n] = sum_k A[m,k]*Bw[n,k] + bias[n]
// XOR-swizzled LDS (no padding, 16-B ops, bank-balanced).
// EPI==0: plain write. EPI==2: write + per-(row, block) softmax partials
//         aux[m*nblk+bx] = rowmax, aux[256*nblk + m*nblk+bx] = sumexp.
// ---------------------------------------------------------------------------
template<int BM, int BN, int WAVES_M, int WAVES_N, int EPI>
__global__ __launch_bounds__(256, 2)
void gemm_f16(const float* __restrict__ A, const float* __restrict__ Bw,
              float* __restrict__ C, const float* __restrict__ bias,
              float* __restrict__ aux, int K, int lda, int ldb, int ldc, int nblk)
{
    constexpr int BK = 32;
    constexpr int WM = BM / WAVES_M;
    constexpr int WN = BN / WAVES_N;
    constexpr int FM = WM / 16;
    constexpr int FN = WN / 16;
    constexpr int A_ITEMS = (BM * 4) / 256;   // items of 8 floats
    constexpr int B_ITEMS = (BN * 4) / 256;

    __shared__ half_t As[BM * BK];
    __shared__ half_t Bs[BN * BK];

    const int tid  = threadIdx.x;
    const int wid  = tid >> 6;
    const int lane = tid & 63;
    const int wm   = wid % WAVES_M;
    const int wn   = wid / WAVES_M;
    const int bm0  = blockIdx.y * BM;
    const int bn0  = blockIdx.x * BN;
    const int col  = lane & 15;
    const int quad = lane >> 4;
    const int swz  = (quad ^ (col & 3)) * 8;

    floatx4 acc[FM][FN] = {};

    for (int kt = 0; kt < K; kt += BK) {
        float4 ar[A_ITEMS][2], br[B_ITEMS][2];
#pragma unroll
        for (int i = 0; i < A_ITEMS; ++i) {
            int idx = tid + i * 256, row = idx >> 2, ch = idx & 3;
            const float* p = A + (size_t)(bm0 + row) * lda + kt + ch * 8;
            ar[i][0] = *(const float4*)p; ar[i][1] = *(const float4*)(p + 4);
        }
#pragma unroll
        for (int i = 0; i < B_ITEMS; ++i) {
            int idx = tid + i * 256, row = idx >> 2, ch = idx & 3;
            const float* p = Bw + (size_t)(bn0 + row) * ldb + kt + ch * 8;
            br[i][0] = *(const float4*)p; br[i][1] = *(const float4*)(p + 4);
        }
        __syncthreads();   // prior iteration's LDS reads done
#pragma unroll
        for (int i = 0; i < A_ITEMS; ++i) {
            int idx = tid + i * 256, row = idx >> 2, ch = idx & 3;
            int pos = (ch ^ (row & 3)) * 8;
            half8 h;
            h[0] = (half_t)ar[i][0].x; h[1] = (half_t)ar[i][0].y;
            h[2] = (half_t)ar[i][0].z; h[3] = (half_t)ar[i][0].w;
            h[4] = (half_t)ar[i][1].x; h[5] = (half_t)ar[i][1].y;
            h[6] = (half_t)ar[i][1].z; h[7] = (half_t)ar[i][1].w;
            *(half8*)(&As[row * BK + pos]) = h;
        }
#pragma unroll
        for (int i = 0; i < B_ITEMS; ++i) {
            int idx = tid + i * 256, row = idx >> 2, ch = idx & 3;
            int pos = (ch ^ (row & 3)) * 8;
            half8 h;
            h[0] = (half_t)br[i][0].x; h[1] = (half_t)br[i][0].y;
            h[2] = (half_t)br[i][0].z; h[3] = (half_t)br[i][0].w;
            h[4] = (half_t)br[i][1].x; h[5] = (half_t)br[i][1].y;
            h[6] = (half_t)br[i][1].z; h[7] = (half_t)br[i][1].w;
            *(half8*)(&Bs[row * BK + pos]) = h;
        }
        __syncthreads();

        half8 af[FM], bf[FN];
#pragma unroll
        for (int fm = 0; fm < FM; ++fm)
            af[fm] = *(const half8*)(&As[(wm * WM + fm * 16 + col) * BK + swz]);
#pragma unroll
        for (int fn = 0; fn < FN; ++fn)
            bf[fn] = *(const half8*)(&Bs[(wn * WN + fn * 16 + col) * BK + swz]);
#pragma unroll
        for (int fm = 0; fm < FM; ++fm)
#pragma unroll
            for (int fn = 0; fn < FN; ++fn)
                acc[fm][fn] = __builtin_amdgcn_mfma_f32_16x16x32_f16(af[fm], bf[fn], acc[fm][fn], 0, 0, 0);
    }

    if constexpr (EPI == 0) {
#pragma unroll
        for (int fm = 0; fm < FM; ++fm) {
            int m0 = bm0 + wm * WM + fm * 16 + quad * 4;
#pragma unroll
            for (int fn = 0; fn < FN; ++fn) {
                int n = bn0 + wn * WN + fn * 16 + col;
                float bv = bias[n];
#pragma unroll
                for (int r = 0; r < 4; ++r)
                    C[(size_t)(m0 + r) * ldc + n] = acc[fm][fn][r] + bv;
            }
        }
    } else {   // EPI == 2 : write + softmax partials (WAVES_N must be 1)
        const int bx = blockIdx.x;
#pragma unroll
        for (int fm = 0; fm < FM; ++fm) {
            int m0 = bm0 + wm * WM + fm * 16 + quad * 4;
            float vv[FN][4];
#pragma unroll
            for (int fn = 0; fn < FN; ++fn) {
                int n = bn0 + fn * 16 + col;
                float bv = bias[n];
#pragma unroll
                for (int r = 0; r < 4; ++r) {
                    vv[fn][r] = acc[fm][fn][r] + bv;
                    C[(size_t)(m0 + r) * ldc + n] = vv[fn][r];
                }
            }
#pragma unroll
            for (int r = 0; r < 4; ++r) {
                float mx = vv[0][r];
#pragma unroll
                for (int fn = 1; fn < FN; ++fn) mx = fmaxf(mx, vv[fn][r]);
#pragma unroll
                for (int off = 1; off < 16; off <<= 1)
                    mx = fmaxf(mx, __shfl_xor(mx, off, 64));
                float se = 0.f;
#pragma unroll
                for (int fn = 0; fn < FN; ++fn) se += __expf(vv[fn][r] - mx);
#pragma unroll
                for (int off = 1; off < 16; off <<= 1)
                    se += __shfl_xor(se, off, 64);
                if (col == 0) {
                    aux[(size_t)(m0 + r) * nblk + bx] = mx;
                    aux[(size_t)256 * nblk + (size_t)(m0 + r) * nblk + bx] = se;
                }
            }
        }
    }
}

// ---------------------------------------------------------------------------
// Wc GEMM + fused tanh-einsum, one block owns ALL N=512:
// sc_out[m] = sum_n tanh(enc[m,:]@Wc[n,:] + bias[n]) * hidden[b(m), n]
// v3: B fragments read from fragment-major WcT (one contiguous 1 KB block
//     per wave-load, fully coalesced, L2-resident). A double-buffered in LDS,
//     one barrier/phase, next-phase loads issued right after the barrier.
// 512 threads, 8 waves (WAVES_M=1, WAVES_N=8), BM=64, grid=512, 2 blocks/CU.
// ---------------------------------------------------------------------------
__global__ __launch_bounds__(512, 4)
void wc_sc_kernel(const float* __restrict__ enc, const half_t* __restrict__ WcT,
                  const float* __restrict__ bias, const float* __restrict__ hidden,
                  float* __restrict__ sc_out)
{
    __shared__ half_t As[2][64 * 32];   // 2 x 4 KB, XOR-swizzled
    __shared__ float  s_part[8 * 64];

    const int tid  = threadIdx.x;
    const int wid  = tid >> 6;          // wave -> col group of 64
    const int lane = tid & 63;
    const int col  = lane & 15;
    const int quad = lane >> 4;
    const int swz  = (quad ^ (col & 3)) * 8;
    const int bm0  = blockIdx.x * 64;

    // A staging mapping (tid < 256): row = tid>>2, 8-float chunk = tid&3
    const int ar_row = tid >> 2;
    const int ar_ch  = tid & 3;
    const float* aptr = enc + (size_t)(bm0 + ar_row) * 1024 + ar_ch * 8;
    const int a_pos = ar_row * 32 + (ar_ch ^ (ar_row & 3)) * 8;

    // B fragment base: fragment (fn, j=k/32) lives at
    //   WcT + ((wid*4+fn)*32 + j)*512 + quad*128 + col*8   (halfs)
    // -> per wave-load: 64 lanes read one contiguous 1 KB block.
    const half_t* bq = WcT + (size_t)wid * 4 * 16384 + quad * 128 + col * 8;

    floatx4 acc[4][4] = {};
    float4 ar0, ar1;
    half8 bf0[4], bf1[4];

    // prologue: issue loads for tile 0 (j = 0)
    if (tid < 256) { ar0 = *(const float4*)(aptr); ar1 = *(const float4*)(aptr + 4); }
#pragma unroll
    for (int fn = 0; fn < 4; ++fn)
        bf0[fn] = *(const half8*)(bq + fn * 16384);

    for (int t2 = 0; t2 < 16; ++t2) {
        const int kA = t2 * 64;
        // ---------- phase A: k-tile j=2*t2, As[0], bf0 ----------
        if (tid < 256) {
            half8 h;
            h[0] = (half_t)ar0.x; h[1] = (half_t)ar0.y; h[2] = (half_t)ar0.z; h[3] = (half_t)ar0.w;
            h[4] = (half_t)ar1.x; h[5] = (half_t)ar1.y; h[6] = (half_t)ar1.z; h[7] = (half_t)ar1.w;
            *(half8*)(&As[0][a_pos]) = h;
        }
        __syncthreads();
        // issue loads for k-tile j=2*t2+1 (hide under phase-A MFMAs)
        if (tid < 256) {
            ar0 = *(const float4*)(aptr + kA + 32);
            ar1 = *(const float4*)(aptr + kA + 36);
        }
#pragma unroll
        for (int fn = 0; fn < 4; ++fn)
            bf1[fn] = *(const half8*)(bq + fn * 16384 + (2 * t2 + 1) * 512);
#pragma unroll
        for (int fm = 0; fm < 4; ++fm) {
            half8 af = *(const half8*)(&As[0][(fm * 16 + col) * 32 + swz]);
#pragma unroll
            for (int fn = 0; fn < 4; ++fn)
                acc[fm][fn] = __builtin_amdgcn_mfma_f32_16x16x32_f16(af, bf0[fn], acc[fm][fn], 0, 0, 0);
        }
        // ---------- phase B: k-tile j=2*t2+1, As[1], bf1 ----------
        if (tid < 256) {
            half8 h;
            h[0] = (half_t)ar0.x; h[1] = (half_t)ar0.y; h[2] = (half_t)ar0.z; h[3] = (half_t)ar0.w;
            h[4] = (half_t)ar1.x; h[5] = (half_t)ar1.y; h[6] = (half_t)ar1.z; h[7] = (half_t)ar1.w;
            *(half8*)(&As[1][a_pos]) = h;
        }
        __syncthreads();
        if (t2 < 15) {   // issue loads for k-tile j=2*t2+2
            if (tid < 256) {
                ar0 = *(const float4*)(aptr + kA + 64);
                ar1 = *(const float4*)(aptr + kA + 68);
            }
#pragma unroll
            for (int fn = 0; fn < 4; ++fn)
                bf0[fn] = *(const half8*)(bq + fn * 16384 + (2 * t2 + 2) * 512);
        }
#pragma unroll
        for (int fm = 0; fm < 4; ++fm) {
            half8 af = *(const half8*)(&As[1][(fm * 16 + col) * 32 + swz]);
#pragma unroll
            for (int fn = 0; fn < 4; ++fn)
                acc[fm][fn] = __builtin_amdgcn_mfma_f32_16x16x32_f16(af, bf1[fn], acc[fm][fn], 0, 0, 0);
        }
    }

    // fused epilogue: tanh + dot with hidden, reduce over n
    const float* hid = hidden + (size_t)(bm0 >> 7) * H_;
#pragma unroll
    for (int fm = 0; fm < 4; ++fm) {
        float p0 = 0.f, p1 = 0.f, p2 = 0.f, p3 = 0.f;
#pragma unroll
        for (int fn = 0; fn < 4; ++fn) {
            int n = wid * 64 + fn * 16 + col;
            float bv = bias[n];
            float hv = hid[n];
            p0 += fast_tanh(acc[fm][fn][0] + bv) * hv;
            p1 += fast_tanh(acc[fm][fn][1] + bv) * hv;
            p2 += fast_tanh(acc[fm][fn][2] + bv) * hv;
            p3 += fast_tanh(acc[fm][fn][3] + bv) * hv;
        }
#pragma unroll
        for (int off = 1; off < 16; off <<= 1) {
            p0 += __shfl_xor(p0, off, 64);
            p1 += __shfl_xor(p1, off, 64);
            p2 += __shfl_xor(p2, off, 64);
            p3 += __shfl_xor(p3, off, 64);
        }
        if (col == 0) {
            int rloc = fm * 16 + quad * 4;   // [0,64)
            s_part[wid * 64 + rloc + 0] = p0;
            s_part[wid * 64 + rloc + 1] = p1;
            s_part[wid * 64 + rloc + 2] = p2;
            s_part[wid * 64 + rloc + 3] = p3;
        }
    }
    __syncthreads();
    if (tid < 64) {
        float s = 0.f;
#pragma unroll
        for (int w = 0; w < 8; ++w) s += s_part[w * 64 + tid];
        sc_out[bm0 + tid] = s;
    }
}

// ---------------------------------------------------------------------------
// GRU gates
// ---------------------------------------------------------------------------
__global__ __launch_bounds__(256)
void gate_kernel(const float* __restrict__ gi, const float* __restrict__ gh,
                 const float* __restrict__ prev, float* __restrict__ hidden)
{
    int i = blockIdx.x * 256 + threadIdx.x;   // B_*H_
    int b = i >> 9;
    int h = i & 511;
    const float* gib = gi + (size_t)b * 1536;
    const float* ghb = gh + (size_t)b * 1536;
    float r = sigmoidf_(gib[h] + ghb[h]);
    float z = sigmoidf_(gib[h + 512] + ghb[h + 512]);
    float n = tanhf(gib[h + 1024] + r * ghb[h + 1024]);
    hidden[i] = (1.0f - z) * n + z * prev[i];
}

// ---------------------------------------------------------------------------
// final: merge softmax partials (from score_g GEMM epilogue) + copy scores,
// single in-place exp pass over predicted (float4), scatter, weighted_out.
// ---------------------------------------------------------------------------
__global__ __launch_bounds__(256)
void final_kernel(const float* __restrict__ sc_raw,
                  const int* __restrict__ src, const int* __restrict__ ids,
                  const float* __restrict__ encoded, const float* __restrict__ parts,
                  float* __restrict__ predicted, float* __restrict__ weighted_out)
{
    int b = blockIdx.x;
    int t = threadIdx.x;
    __shared__ float s_scf[S_];
    __shared__ float s_attn[S_];
    __shared__ int   s_src[S_];
    __shared__ float rm[4], rs[4];
    __shared__ int   s_cnt;

    float* pred = predicted + (size_t)b * V_;
    const float* pm = parts + (size_t)b * NBLK_G;
    const float* ps = parts + (size_t)256 * NBLK_G + (size_t)b * NBLK_G;

    if (t < S_) {
        int sv = src[b * S_ + t];
        s_src[t] = sv;
        float raw = sc_raw[b * S_ + t];
        if (sv == 0) raw -= 1000.0f;
        s_scf[t] = tanhf(raw);
    }

    // merge (max, sumexp) partials
    float m = -1e30f, s = 0.f;
    for (int j = t; j < NBLK_G; j += 256) {
        float mo = pm[j], so = ps[j];
        float mn = fmaxf(m, mo);
        s = s * __expf(m - mn) + so * __expf(mo - mn);
        m = mn;
    }
    __syncthreads();
    if (t < S_) {
        float x = s_scf[t];
        float mn = fmaxf(m, x);
        s = s * __expf(m - mn) + __expf(x - mn);
        m = mn;
    }
#pragma unroll
    for (int off = 1; off < 64; off <<= 1) {
        float mo = __shfl_xor(m, off, 64);
        float so = __shfl_xor(s, off, 64);
        float mn = fmaxf(m, mo);
        s = s * __expf(m - mn) + so * __expf(mo - mn);
        m = mn;
    }
    if ((t & 63) == 0) { rm[t >> 6] = m; rs[t >> 6] = s; }
    __syncthreads();
    float M = rm[0], Z = rs[0];
#pragma unroll
    for (int w = 1; w < 4; ++w) {
        float mo = rm[w], so = rs[w];
        float mn = fmaxf(M, mo);
        Z = Z * __expf(M - mn) + so * __expf(mo - mn);
        M = mn;
    }
    float invZ = 1.0f / Z;

    // in-place: predicted currently holds score_g
    float4* pr4 = (float4*)pred;
    for (int i = t; i < V_ / 4; i += 256) {
        float4 x = pr4[i];
        float4 o;
        o.x = __expf(x.x - M) * invZ;
        o.y = __expf(x.y - M) * invZ;
        o.z = __expf(x.z - M) * invZ;
        o.w = __expf(x.w - M) * invZ;
        pr4[i] = o;
    }

    int ii = ids[b];
    if (t == 0) {
        int c = 0;
        for (int s2 = 0; s2 < S_; ++s2) c += (s_src[s2] == ii) ? 1 : 0;
        s_cnt = (c > 0) ? c : 1;
    }
    __syncthreads();   // prob_g writes drained before scatter atomics

    if (t < S_) {
        float pc = __expf(s_scf[t] - M) * invZ;
        atomicAdd(&pred[s_src[t]], pc);
        s_attn[t] = (s_src[t] == ii) ? pc / (float)s_cnt : 0.f;
    }
    __syncthreads();

    const float* eb = encoded + (size_t)b * S_ * 1024;
    for (int d = t; d < 1024; d += 256) {
        float accv = 0.f;
        for (int s2 = 0; s2 < S_; ++s2) {
            float a = s_attn[s2];
            if (a != 0.f) accv += a * eb[s2 * 1024 + d];
        }
        weighted_out[b * 1024 + d] = accv;
    }
}

// ---------------------------------------------------------------------------
extern "C" void kernel_launch(void* const* d_in, const int* in_sizes, int n_in,
                              void* d_out, int out_size, void* d_ws, size_t ws_size,
                              hipStream_t stream)
{
    const int*   input_ids  = (const int*)d_in[0];
    const float* encoded    = (const float*)d_in[1];
    const int*   src        = (const int*)d_in[2];
    const float* prev_state = (const float*)d_in[3];
    const float* weighted   = (const float*)d_in[4];
    const int*   order      = (const int*)d_in[5];
    const float* embed_w    = (const float*)d_in[6];
    const float* gru_w_ih   = (const float*)d_in[7];
    const float* gru_w_hh   = (const float*)d_in[8];
    const float* gru_b_ih   = (const float*)d_in[9];
    const float* gru_b_hh   = (const float*)d_in[10];
    const float* Ws_w       = (const float*)d_in[11];
    const float* Ws_b       = (const float*)d_in[12];
    const float* Wo_w       = (const float*)d_in[13];
    const float* Wo_b       = (const float*)d_in[14];
    const float* Wc_w       = (const float*)d_in[15];
    const float* Wc_b       = (const float*)d_in[16];
    (void)in_sizes; (void)n_in; (void)out_size; (void)ws_size;

    float* predicted    = (float*)d_out;                       // B*V (holds score_g first)
    float* hidden       = predicted + (size_t)B_ * V_;         // B*H
    float* weighted_out = hidden + (size_t)B_ * H_;            // B*2H

    char* w = (char*)d_ws;
    float* x_f32  = (float*)w;  w += (size_t)B_ * 1536 * 4;
    float* prev_f = (float*)w;  w += (size_t)B_ * H_ * 4;
    float* gi     = (float*)w;  w += (size_t)B_ * 1536 * 4;
    float* gh     = (float*)w;  w += (size_t)B_ * 1536 * 4;
    float* sc_raw = (float*)w;  w += (size_t)B_ * S_ * 4;
    float* parts  = (float*)w;  w += (size_t)2 * B_ * NBLK_G * 4;
    half_t* wc_h  = (half_t*)w; w += (size_t)H_ * 1024 * 2;    // 1 MB f16 Wc (fragment-major)

    // Wc -> f16 fragment-major once (2 MB read), ahead so L2 is warm for wc_sc
    wc_cvt_kernel<<<256, 256, 0, stream>>>(Wc_w, wc_h);

    prep_kernel<<<2048, 256, 0, stream>>>(input_ids, encoded, prev_state, weighted,
                                          order, embed_w, Ws_w, Ws_b, x_f32, prev_f);

    // gi = x @ W_ih^T + b_ih   (M=256, N=1536, K=1536)
    gemm_f16<64, 64, 2, 2, 0><<<dim3(1536 / 64, 256 / 64), 256, 0, stream>>>(
        x_f32, gru_w_ih, gi, gru_b_ih, nullptr, 1536, 1536, 1536, 1536, 0);
    // gh = prev @ W_hh^T + b_hh  (M=256, N=1536, K=512)
    gemm_f16<64, 64, 2, 2, 0><<<dim3(1536 / 64, 256 / 64), 256, 0, stream>>>(
        prev_f, gru_w_hh, gh, gru_b_hh, nullptr, 512, 512, 512, 1536, 0);

    gate_kernel<<<(B_ * H_) / 256, 256, 0, stream>>>(gi, gh, prev_f, hidden);

    // sc_raw[b,s] (fused tanh-einsum), encoded read exactly once
    wc_sc_kernel<<<(B_ * S_) / 64, 512, 0, stream>>>(encoded, wc_h, Wc_b, hidden, sc_raw);

    // score_g -> predicted (in-place later) + softmax partials
    gemm_f16<256, 64, 4, 1, 2><<<dim3(NBLK_G, 1), 256, 0, stream>>>(
        hidden, Wo_w, predicted, Wo_b, parts, 512, 512, 512, V_, NBLK_G);

    final_kernel<<<B_, 256, 0, stream>>>(sc_raw, src, input_ids, encoded, parts,
                                         predicted, weighted_out);
}

// Round 3
// 414.931 us; speedup vs baseline: 1.2234x; 1.0851x over previous
//
#include <hip/hip_runtime.h>
#include <cstdint>
#include <cstddef>

#define B_ 256
#define S_ 128
#define H_ 512
#define E_ 512
#define V_ 32000
#define NBLK_G (V_ / 64)   // 500 column blocks in score_g GEMM

typedef _Float16 half_t;
typedef _Float16 half8 __attribute__((ext_vector_type(8)));
typedef float floatx4 __attribute__((ext_vector_type(4)));

__device__ __forceinline__ float sigmoidf_(float x) { return 1.0f / (1.0f + __expf(-x)); }
__device__ __forceinline__ float fast_tanh(float x) {
    float e = __expf(2.0f * x);           // +-inf safe: -> -1 / +1
    return 1.0f - 2.0f / (e + 1.0f);
}

// ---------------------------------------------------------------------------
// prep (blocks < 2048): x = [embed[ids], weighted_eff] (B,1536), prev_eff.
// blocks >= 2048: Wc fp32 -> f16 fragment-major (wc_cvt merged in):
//   out[(((nt*32 + kt)*4 + kq)*16 + nc)*8 + e] = Wc[nt*16+nc][kt*32+kq*8+e]
// ---------------------------------------------------------------------------
__global__ __launch_bounds__(256)
void prep_kernel(const int* __restrict__ ids, const float* __restrict__ encoded,
                 const float* __restrict__ prev_state, const float* __restrict__ weighted,
                 const int* __restrict__ order_p, const float* __restrict__ embed,
                 const float* __restrict__ Ws_w, const float* __restrict__ Ws_b,
                 float* __restrict__ x, float* __restrict__ prev,
                 const float* __restrict__ Wc, half_t* __restrict__ wc_out)
{
    if (blockIdx.x >= 2048) {
        int i = (blockIdx.x - 2048) * 256 + threadIdx.x;   // 65536 chunks of 8
        int nc = i & 15;
        int kq = (i >> 4) & 3;
        int kt = (i >> 6) & 31;
        int nt = i >> 11;
        const float* p = Wc + (size_t)(nt * 16 + nc) * 1024 + kt * 32 + kq * 8;
        float4 a = *(const float4*)p;
        float4 b = *(const float4*)(p + 4);
        half8 h;
        h[0] = (half_t)a.x; h[1] = (half_t)a.y; h[2] = (half_t)a.z; h[3] = (half_t)a.w;
        h[4] = (half_t)b.x; h[5] = (half_t)b.y; h[6] = (half_t)b.z; h[7] = (half_t)b.w;
        *(half8*)(wc_out + (size_t)i * 8) = h;
        return;
    }
    int i = blockIdx.x * 256 + threadIdx.x;   // B_ * 2048 threads
    int b = i >> 11;
    int j = i & 2047;
    int order = order_p[0];
    if (j < 1536) {
        float v;
        if (j < 512) v = embed[(size_t)ids[b] * E_ + j];
        else         v = (order == 0) ? 0.0f : weighted[b * 1024 + (j - 512)];
        x[b * 1536 + j] = v;
    } else {
        int h = j - 1536;
        float v;
        if (order != 0) {
            v = prev_state[b * H_ + h];
        } else {
            const float* e  = encoded + ((size_t)b * S_ + (S_ - 1)) * 1024;
            const float* wr = Ws_w + (size_t)h * 1024;
            float accv = Ws_b[h];
            for (int k = 0; k < 1024; ++k) accv += e[k] * wr[k];
            v = accv;
        }
        prev[b * H_ + h] = v;
    }
}

// ---------------------------------------------------------------------------
// Generic fp32-in / fp16-MFMA GEMM: C[m,n] = sum_k A[m,k]*Bw[n,k] + bias[n]
// XOR-swizzled LDS. EPI==0: plain write. EPI==2: write + softmax partials.
// ---------------------------------------------------------------------------
template<int BM, int BN, int WAVES_M, int WAVES_N, int EPI>
__global__ __launch_bounds__(256, 2)
void gemm_f16(const float* __restrict__ A, const float* __restrict__ Bw,
              float* __restrict__ C, const float* __restrict__ bias,
              float* __restrict__ aux, int K, int lda, int ldb, int ldc, int nblk)
{
    constexpr int BK = 32;
    constexpr int WM = BM / WAVES_M;
    constexpr int WN = BN / WAVES_N;
    constexpr int FM = WM / 16;
    constexpr int FN = WN / 16;
    constexpr int A_ITEMS = (BM * 4) / 256;   // items of 8 floats
    constexpr int B_ITEMS = (BN * 4) / 256;

    __shared__ half_t As[BM * BK];
    __shared__ half_t Bs[BN * BK];

    const int tid  = threadIdx.x;
    const int wid  = tid >> 6;
    const int lane = tid & 63;
    const int wm   = wid % WAVES_M;
    const int wn   = wid / WAVES_M;
    const int bm0  = blockIdx.y * BM;
    const int bn0  = blockIdx.x * BN;
    const int col  = lane & 15;
    const int quad = lane >> 4;
    const int swz  = (quad ^ (col & 3)) * 8;

    floatx4 acc[FM][FN] = {};

    for (int kt = 0; kt < K; kt += BK) {
        float4 ar[A_ITEMS][2], br[B_ITEMS][2];
#pragma unroll
        for (int i = 0; i < A_ITEMS; ++i) {
            int idx = tid + i * 256, row = idx >> 2, ch = idx & 3;
            const float* p = A + (size_t)(bm0 + row) * lda + kt + ch * 8;
            ar[i][0] = *(const float4*)p; ar[i][1] = *(const float4*)(p + 4);
        }
#pragma unroll
        for (int i = 0; i < B_ITEMS; ++i) {
            int idx = tid + i * 256, row = idx >> 2, ch = idx & 3;
            const float* p = Bw + (size_t)(bn0 + row) * ldb + kt + ch * 8;
            br[i][0] = *(const float4*)p; br[i][1] = *(const float4*)(p + 4);
        }
        __syncthreads();   // prior iteration's LDS reads done
#pragma unroll
        for (int i = 0; i < A_ITEMS; ++i) {
            int idx = tid + i * 256, row = idx >> 2, ch = idx & 3;
            int pos = (ch ^ (row & 3)) * 8;
            half8 h;
            h[0] = (half_t)ar[i][0].x; h[1] = (half_t)ar[i][0].y;
            h[2] = (half_t)ar[i][0].z; h[3] = (half_t)ar[i][0].w;
            h[4] = (half_t)ar[i][1].x; h[5] = (half_t)ar[i][1].y;
            h[6] = (half_t)ar[i][1].z; h[7] = (half_t)ar[i][1].w;
            *(half8*)(&As[row * BK + pos]) = h;
        }
#pragma unroll
        for (int i = 0; i < B_ITEMS; ++i) {
            int idx = tid + i * 256, row = idx >> 2, ch = idx & 3;
            int pos = (ch ^ (row & 3)) * 8;
            half8 h;
            h[0] = (half_t)br[i][0].x; h[1] = (half_t)br[i][0].y;
            h[2] = (half_t)br[i][0].z; h[3] = (half_t)br[i][0].w;
            h[4] = (half_t)br[i][1].x; h[5] = (half_t)br[i][1].y;
            h[6] = (half_t)br[i][1].z; h[7] = (half_t)br[i][1].w;
            *(half8*)(&Bs[row * BK + pos]) = h;
        }
        __syncthreads();

        half8 af[FM], bf[FN];
#pragma unroll
        for (int fm = 0; fm < FM; ++fm)
            af[fm] = *(const half8*)(&As[(wm * WM + fm * 16 + col) * BK + swz]);
#pragma unroll
        for (int fn = 0; fn < FN; ++fn)
            bf[fn] = *(const half8*)(&Bs[(wn * WN + fn * 16 + col) * BK + swz]);
#pragma unroll
        for (int fm = 0; fm < FM; ++fm)
#pragma unroll
            for (int fn = 0; fn < FN; ++fn)
                acc[fm][fn] = __builtin_amdgcn_mfma_f32_16x16x32_f16(af[fm], bf[fn], acc[fm][fn], 0, 0, 0);
    }

    if constexpr (EPI == 0) {
#pragma unroll
        for (int fm = 0; fm < FM; ++fm) {
            int m0 = bm0 + wm * WM + fm * 16 + quad * 4;
#pragma unroll
            for (int fn = 0; fn < FN; ++fn) {
                int n = bn0 + wn * WN + fn * 16 + col;
                float bv = bias[n];
#pragma unroll
                for (int r = 0; r < 4; ++r)
                    C[(size_t)(m0 + r) * ldc + n] = acc[fm][fn][r] + bv;
            }
        }
    } else {   // EPI == 2 : write + softmax partials (WAVES_N must be 1)
        const int bx = blockIdx.x;
#pragma unroll
        for (int fm = 0; fm < FM; ++fm) {
            int m0 = bm0 + wm * WM + fm * 16 + quad * 4;
            float vv[FN][4];
#pragma unroll
            for (int fn = 0; fn < FN; ++fn) {
                int n = bn0 + fn * 16 + col;
                float bv = bias[n];
#pragma unroll
                for (int r = 0; r < 4; ++r) {
                    vv[fn][r] = acc[fm][fn][r] + bv;
                    C[(size_t)(m0 + r) * ldc + n] = vv[fn][r];
                }
            }
#pragma unroll
            for (int r = 0; r < 4; ++r) {
                float mx = vv[0][r];
#pragma unroll
                for (int fn = 1; fn < FN; ++fn) mx = fmaxf(mx, vv[fn][r]);
#pragma unroll
                for (int off = 1; off < 16; off <<= 1)
                    mx = fmaxf(mx, __shfl_xor(mx, off, 64));
                float se = 0.f;
#pragma unroll
                for (int fn = 0; fn < FN; ++fn) se += __expf(vv[fn][r] - mx);
#pragma unroll
                for (int off = 1; off < 16; off <<= 1)
                    se += __shfl_xor(se, off, 64);
                if (col == 0) {
                    aux[(size_t)(m0 + r) * nblk + bx] = mx;
                    aux[(size_t)256 * nblk + (size_t)(m0 + r) * nblk + bx] = se;
                }
            }
        }
    }
}

// ---------------------------------------------------------------------------
// GRU dual GEMM: gi = x @ W_ih^T + b_ih  AND  gh = prev @ W_hh^T + b_hh
// in ONE launch (both under-occupy alone; merged they run concurrently).
// grid (48, 4): bx<24 -> gi (K=1536), bx>=24 -> gh (K=512). BM=BN=64, 2x2 waves.
// ---------------------------------------------------------------------------
__global__ __launch_bounds__(256, 2)
void gru_gemm(const float* __restrict__ x, const float* __restrict__ prevf,
              const float* __restrict__ Wih, const float* __restrict__ Whh,
              const float* __restrict__ bih, const float* __restrict__ bhh,
              float* __restrict__ gi, float* __restrict__ gh)
{
    constexpr int BK = 32;
    __shared__ half_t As[64 * BK];
    __shared__ half_t Bs[64 * BK];

    const int sel = (blockIdx.x >= 24) ? 1 : 0;
    const float* A    = sel ? prevf : x;
    const float* Bw   = sel ? Whh : Wih;
    float*       C    = sel ? gh : gi;
    const float* bias = sel ? bhh : bih;
    const int K   = sel ? 512 : 1536;
    const int lda = sel ? 512 : 1536;
    const int ldb = lda;
    const int bn0 = (sel ? blockIdx.x - 24 : blockIdx.x) * 64;
    const int bm0 = blockIdx.y * 64;

    const int tid  = threadIdx.x;
    const int wid  = tid >> 6;
    const int lane = tid & 63;
    const int wm   = wid & 1;
    const int wn   = wid >> 1;
    const int col  = lane & 15;
    const int quad = lane >> 4;
    const int swz  = (quad ^ (col & 3)) * 8;

    floatx4 acc[2][2] = {};

    for (int kt = 0; kt < K; kt += BK) {
        int row = tid >> 2, ch = tid & 3;
        const float* pa = A + (size_t)(bm0 + row) * lda + kt + ch * 8;
        const float* pb = Bw + (size_t)(bn0 + row) * ldb + kt + ch * 8;
        float4 a0 = *(const float4*)pa, a1 = *(const float4*)(pa + 4);
        float4 b0 = *(const float4*)pb, b1 = *(const float4*)(pb + 4);
        __syncthreads();
        int pos = row * BK + (ch ^ (row & 3)) * 8;
        half8 ha, hb;
        ha[0] = (half_t)a0.x; ha[1] = (half_t)a0.y; ha[2] = (half_t)a0.z; ha[3] = (half_t)a0.w;
        ha[4] = (half_t)a1.x; ha[5] = (half_t)a1.y; ha[6] = (half_t)a1.z; ha[7] = (half_t)a1.w;
        hb[0] = (half_t)b0.x; hb[1] = (half_t)b0.y; hb[2] = (half_t)b0.z; hb[3] = (half_t)b0.w;
        hb[4] = (half_t)b1.x; hb[5] = (half_t)b1.y; hb[6] = (half_t)b1.z; hb[7] = (half_t)b1.w;
        *(half8*)(&As[pos]) = ha;
        *(half8*)(&Bs[pos]) = hb;
        __syncthreads();

        half8 af[2], bf[2];
#pragma unroll
        for (int fm = 0; fm < 2; ++fm)
            af[fm] = *(const half8*)(&As[(wm * 32 + fm * 16 + col) * BK + swz]);
#pragma unroll
        for (int fn = 0; fn < 2; ++fn)
            bf[fn] = *(const half8*)(&Bs[(wn * 32 + fn * 16 + col) * BK + swz]);
#pragma unroll
        for (int fm = 0; fm < 2; ++fm)
#pragma unroll
            for (int fn = 0; fn < 2; ++fn)
                acc[fm][fn] = __builtin_amdgcn_mfma_f32_16x16x32_f16(af[fm], bf[fn], acc[fm][fn], 0, 0, 0);
    }

#pragma unroll
    for (int fm = 0; fm < 2; ++fm) {
        int m0 = bm0 + wm * 32 + fm * 16 + quad * 4;
#pragma unroll
        for (int fn = 0; fn < 2; ++fn) {
            int n = bn0 + wn * 32 + fn * 16 + col;
            float bv = bias[n];
#pragma unroll
            for (int r = 0; r < 4; ++r)
                C[(size_t)(m0 + r) * 1536 + n] = acc[fm][fn][r] + bv;
        }
    }
}

// ---------------------------------------------------------------------------
// Wc GEMM + fused tanh-einsum, one block owns ALL N=512:
// v4: BK=64 (32 MFMAs per barrier, 16 phases), B fragments direct from
//     fragment-major WcT (L2), A double-buffered in LDS (2x8 KB), one
//     barrier/phase, s_setprio around the MFMA cluster.
// 512 threads, 8 waves (each owns 64 cols), BM=64, grid=512, 2 blocks/CU.
// ---------------------------------------------------------------------------
__global__ __launch_bounds__(512, 4)
void wc_sc_kernel(const float* __restrict__ enc, const half_t* __restrict__ WcT,
                  const float* __restrict__ bias, const float* __restrict__ hidden,
                  float* __restrict__ sc_out)
{
    __shared__ half_t As[2][64 * 64];   // 2 x 8 KB, XOR-swizzled (8 chunks/row)
    __shared__ float  s_part[8 * 64];

    const int tid  = threadIdx.x;
    const int wid  = tid >> 6;          // wave -> col group of 64
    const int lane = tid & 63;
    const int col  = lane & 15;
    const int quad = lane >> 4;
    const int bm0  = blockIdx.x * 64;

    // A staging: all 512 threads, row = tid>>3, 8-float chunk = tid&7
    const int ar_row = tid >> 3;
    const int ar_ch  = tid & 7;
    const float* aptr = enc + (size_t)(bm0 + ar_row) * 1024 + ar_ch * 8;
    const int a_pos = ar_row * 64 + ((ar_ch ^ (ar_row & 7)) * 8);

    // B fragment base: fragment (fn, jt=k/32) at
    //   WcT + (wid*4+fn)*16384 + jt*512 + quad*128 + col*8  (one 1 KB block/wave)
    const half_t* bq = WcT + (size_t)wid * 65536 + quad * 128 + col * 8;

    floatx4 acc[4][4] = {};
    float4 ar0, ar1;

    // preload A tile 0 (k 0..63)
    ar0 = *(const float4*)(aptr);
    ar1 = *(const float4*)(aptr + 4);

    for (int ph = 0; ph < 16; ++ph) {
        const int buf = ph & 1;
        {   // write current A tile (vmcnt wait on ar is compiler-inserted)
            half8 h;
            h[0] = (half_t)ar0.x; h[1] = (half_t)ar0.y; h[2] = (half_t)ar0.z; h[3] = (half_t)ar0.w;
            h[4] = (half_t)ar1.x; h[5] = (half_t)ar1.y; h[6] = (half_t)ar1.z; h[7] = (half_t)ar1.w;
            *(half8*)(&As[buf][a_pos]) = h;
        }
        __syncthreads();
        // prefetch next A tile (regs) — latency hides under this phase's MFMAs
        if (ph < 15) {
            ar0 = *(const float4*)(aptr + (ph + 1) * 64);
            ar1 = *(const float4*)(aptr + (ph + 1) * 64 + 4);
        }
        // B fragments for this phase: jt = 2*ph, 2*ph+1 (8 x 16B, L2, coalesced)
        half8 bf[2][4];
#pragma unroll
        for (int j = 0; j < 2; ++j)
#pragma unroll
            for (int fn = 0; fn < 4; ++fn)
                bf[j][fn] = *(const half8*)(bq + (size_t)fn * 16384 + (2 * ph + j) * 512);

        __builtin_amdgcn_s_setprio(1);
#pragma unroll
        for (int fm = 0; fm < 4; ++fm) {
            const int row = fm * 16 + col;
#pragma unroll
            for (int j = 0; j < 2; ++j) {
                half8 af = *(const half8*)(&As[buf][row * 64 + (((j * 4 + quad) ^ (row & 7)) * 8)]);
#pragma unroll
                for (int fn = 0; fn < 4; ++fn)
                    acc[fm][fn] = __builtin_amdgcn_mfma_f32_16x16x32_f16(af, bf[j][fn], acc[fm][fn], 0, 0, 0);
            }
        }
        __builtin_amdgcn_s_setprio(0);
    }

    // fused epilogue: tanh + dot with hidden, reduce over n
    const float* hid = hidden + (size_t)(bm0 >> 7) * H_;
#pragma unroll
    for (int fm = 0; fm < 4; ++fm) {
        float p0 = 0.f, p1 = 0.f, p2 = 0.f, p3 = 0.f;
#pragma unroll
        for (int fn = 0; fn < 4; ++fn) {
            int n = wid * 64 + fn * 16 + col;
            float bv = bias[n];
            float hv = hid[n];
            p0 += fast_tanh(acc[fm][fn][0] + bv) * hv;
            p1 += fast_tanh(acc[fm][fn][1] + bv) * hv;
            p2 += fast_tanh(acc[fm][fn][2] + bv) * hv;
            p3 += fast_tanh(acc[fm][fn][3] + bv) * hv;
        }
#pragma unroll
        for (int off = 1; off < 16; off <<= 1) {
            p0 += __shfl_xor(p0, off, 64);
            p1 += __shfl_xor(p1, off, 64);
            p2 += __shfl_xor(p2, off, 64);
            p3 += __shfl_xor(p3, off, 64);
        }
        if (col == 0) {
            int rloc = fm * 16 + quad * 4;   // [0,64)
            s_part[wid * 64 + rloc + 0] = p0;
            s_part[wid * 64 + rloc + 1] = p1;
            s_part[wid * 64 + rloc + 2] = p2;
            s_part[wid * 64 + rloc + 3] = p3;
        }
    }
    __syncthreads();
    if (tid < 64) {
        float s = 0.f;
#pragma unroll
        for (int w = 0; w < 8; ++w) s += s_part[w * 64 + tid];
        sc_out[bm0 + tid] = s;
    }
}

// ---------------------------------------------------------------------------
// GRU gates
// ---------------------------------------------------------------------------
__global__ __launch_bounds__(256)
void gate_kernel(const float* __restrict__ gi, const float* __restrict__ gh,
                 const float* __restrict__ prev, float* __restrict__ hidden)
{
    int i = blockIdx.x * 256 + threadIdx.x;   // B_*H_
    int b = i >> 9;
    int h = i & 511;
    const float* gib = gi + (size_t)b * 1536;
    const float* ghb = gh + (size_t)b * 1536;
    float r = sigmoidf_(gib[h] + ghb[h]);
    float z = sigmoidf_(gib[h + 512] + ghb[h + 512]);
    float n = tanhf(gib[h + 1024] + r * ghb[h + 1024]);
    hidden[i] = (1.0f - z) * n + z * prev[i];
}

// ---------------------------------------------------------------------------
// final: merge softmax partials + scores, in-place exp pass over predicted,
// scatter, weighted_out. v2: 1024 threads (4x parallel exp pass; one thread
// per weighted_out dim).
// ---------------------------------------------------------------------------
__global__ __launch_bounds__(1024)
void final_kernel(const float* __restrict__ sc_raw,
                  const int* __restrict__ src, const int* __restrict__ ids,
                  const float* __restrict__ encoded, const float* __restrict__ parts,
                  float* __restrict__ predicted, float* __restrict__ weighted_out)
{
    int b = blockIdx.x;
    int t = threadIdx.x;
    __shared__ float s_scf[S_];
    __shared__ float s_attn[S_];
    __shared__ int   s_src[S_];
    __shared__ float rm[16], rs[16];
    __shared__ int   s_cnt;

    float* pred = predicted + (size_t)b * V_;
    const float* pm = parts + (size_t)b * NBLK_G;
    const float* ps = parts + (size_t)256 * NBLK_G + (size_t)b * NBLK_G;

    if (t < S_) {
        int sv = src[b * S_ + t];
        s_src[t] = sv;
        float raw = sc_raw[b * S_ + t];
        if (sv == 0) raw -= 1000.0f;
        s_scf[t] = tanhf(raw);
    }

    // merge (max, sumexp) partials: thread t owns partial t (t < 500)
    float m = -1e30f, s = 0.f;
    for (int j = t; j < NBLK_G; j += 1024) {
        float mo = pm[j], so = ps[j];
        float mn = fmaxf(m, mo);
        s = s * __expf(m - mn) + so * __expf(mo - mn);
        m = mn;
    }
    __syncthreads();
    if (t < S_) {
        float x = s_scf[t];
        float mn = fmaxf(m, x);
        s = s * __expf(m - mn) + __expf(x - mn);
        m = mn;
    }
#pragma unroll
    for (int off = 1; off < 64; off <<= 1) {
        float mo = __shfl_xor(m, off, 64);
        float so = __shfl_xor(s, off, 64);
        float mn = fmaxf(m, mo);
        s = s * __expf(m - mn) + so * __expf(mo - mn);
        m = mn;
    }
    if ((t & 63) == 0) { rm[t >> 6] = m; rs[t >> 6] = s; }
    __syncthreads();
    float M = rm[0], Z = rs[0];
#pragma unroll
    for (int w = 1; w < 16; ++w) {
        float mo = rm[w], so = rs[w];
        float mn = fmaxf(M, mo);
        Z = Z * __expf(M - mn) + so * __expf(mo - mn);
        M = mn;
    }
    float invZ = 1.0f / Z;

    // in-place: predicted currently holds score_g
    float4* pr4 = (float4*)pred;
    for (int i = t; i < V_ / 4; i += 1024) {
        float4 x = pr4[i];
        float4 o;
        o.x = __expf(x.x - M) * invZ;
        o.y = __expf(x.y - M) * invZ;
        o.z = __expf(x.z - M) * invZ;
        o.w = __expf(x.w - M) * invZ;
        pr4[i] = o;
    }

    int ii = ids[b];
    if (t == 0) {
        int c = 0;
        for (int s2 = 0; s2 < S_; ++s2) c += (s_src[s2] == ii) ? 1 : 0;
        s_cnt = (c > 0) ? c : 1;
    }
    __syncthreads();   // prob_g writes drained before scatter atomics

    if (t < S_) {
        float pc = __expf(s_scf[t] - M) * invZ;
        atomicAdd(&pred[s_src[t]], pc);
        s_attn[t] = (s_src[t] == ii) ? pc / (float)s_cnt : 0.f;
    }
    __syncthreads();

    const float* eb = encoded + (size_t)b * S_ * 1024;
    for (int d = t; d < 1024; d += 1024) {
        float accv = 0.f;
        for (int s2 = 0; s2 < S_; ++s2) {
            float a = s_attn[s2];
            if (a != 0.f) accv += a * eb[s2 * 1024 + d];
        }
        weighted_out[b * 1024 + d] = accv;
    }
}

// ---------------------------------------------------------------------------
extern "C" void kernel_launch(void* const* d_in, const int* in_sizes, int n_in,
                              void* d_out, int out_size, void* d_ws, size_t ws_size,
                              hipStream_t stream)
{
    const int*   input_ids  = (const int*)d_in[0];
    const float* encoded    = (const float*)d_in[1];
    const int*   src        = (const int*)d_in[2];
    const float* prev_state = (const float*)d_in[3];
    const float* weighted   = (const float*)d_in[4];
    const int*   order      = (const int*)d_in[5];
    const float* embed_w    = (const float*)d_in[6];
    const float* gru_w_ih   = (const float*)d_in[7];
    const float* gru_w_hh   = (const float*)d_in[8];
    const float* gru_b_ih   = (const float*)d_in[9];
    const float* gru_b_hh   = (const float*)d_in[10];
    const float* Ws_w       = (const float*)d_in[11];
    const float* Ws_b       = (const float*)d_in[12];
    const float* Wo_w       = (const float*)d_in[13];
    const float* Wo_b       = (const float*)d_in[14];
    const float* Wc_w       = (const float*)d_in[15];
    const float* Wc_b       = (const float*)d_in[16];
    (void)in_sizes; (void)n_in; (void)out_size; (void)ws_size;

    float* predicted    = (float*)d_out;                       // B*V (holds score_g first)
    float* hidden       = predicted + (size_t)B_ * V_;         // B*H
    float* weighted_out = hidden + (size_t)B_ * H_;            // B*2H

    char* w = (char*)d_ws;
    float* x_f32  = (float*)w;  w += (size_t)B_ * 1536 * 4;
    float* prev_f = (float*)w;  w += (size_t)B_ * H_ * 4;
    float* gi     = (float*)w;  w += (size_t)B_ * 1536 * 4;
    float* gh     = (float*)w;  w += (size_t)B_ * 1536 * 4;
    float* sc_raw = (float*)w;  w += (size_t)B_ * S_ * 4;
    float* parts  = (float*)w;  w += (size_t)2 * B_ * NBLK_G * 4;
    half_t* wc_h  = (half_t*)w; w += (size_t)H_ * 1024 * 2;    // 1 MB f16 Wc (fragment-major)

    // prep (blocks 0..2047) + Wc->f16 fragment-major (blocks 2048..2303)
    prep_kernel<<<2304, 256, 0, stream>>>(input_ids, encoded, prev_state, weighted,
                                          order, embed_w, Ws_w, Ws_b, x_f32, prev_f,
                                          Wc_w, wc_h);

    // gi and gh concurrently in one launch
    gru_gemm<<<dim3(48, 4), 256, 0, stream>>>(x_f32, prev_f, gru_w_ih, gru_w_hh,
                                              gru_b_ih, gru_b_hh, gi, gh);

    gate_kernel<<<(B_ * H_) / 256, 256, 0, stream>>>(gi, gh, prev_f, hidden);

    // sc_raw[b,s] (fused tanh-einsum), encoded read exactly once
    wc_sc_kernel<<<(B_ * S_) / 64, 512, 0, stream>>>(encoded, wc_h, Wc_b, hidden, sc_raw);

    // score_g -> predicted (in-place later) + softmax partials
    gemm_f16<256, 64, 4, 1, 2><<<dim3(NBLK_G, 1), 256, 0, stream>>>(
        hidden, Wo_w, predicted, Wo_b, parts, 512, 512, 512, V_, NBLK_G);

    final_kernel<<<B_, 1024, 0, stream>>>(sc_raw, src, input_ids, encoded, parts,
                                          predicted, weighted_out);
}